// Round 6
// baseline (316.109 us; speedup 1.0000x reference)
//
#include <hip/hip_runtime.h>
#include <math.h>

typedef __bf16 bf16_t;
typedef bf16_t bf16x4 __attribute__((ext_vector_type(4)));
typedef bf16_t bf16x8 __attribute__((ext_vector_type(8)));
typedef float  f32x16 __attribute__((ext_vector_type(16)));

#define HH 1024
#define CC 8
#define DD 64
#define FF 32
#define WW 7
#define HP 1018
#define HPAD 1024
#define NF 128
#define QOUT (NF*HP*DD)
#define QWS ((size_t)NF*HPAD*DD)
#define SCEXP (1.442695041f/1018.f)     // log2(e)/1018, pre-applied to q1

#if __has_builtin(__builtin_amdgcn_exp2f)
#define EXP2(x) __builtin_amdgcn_exp2f(x)
#else
#define EXP2(x) __expf((x) * 0.6931471805599453f)
#endif

// Vt: row stride 64 bf16, XOR-swizzled 8-element chunks (validated R4/R5):
__device__ __forceinline__ int vaddr(int row, int col) {
    return row*64 + ((((col>>3) ^ (row&7) ^ ((row>>2)&7)))<<3) + (col&7);
}

// ---------------- W transpose: Wt[f][c][d][j] -> Wp[f][c][j][d] ----------------
__global__ __launch_bounds__(256) void wprep_kernel(
    const float* __restrict__ Wt, float* __restrict__ Wp)
{
    const int idx = blockIdx.x * 256 + threadIdx.x;
    if (idx < FF*CC*DD*WW) {
        const int j = idx % WW;
        int t = idx / WW;
        const int d = t % DD; t /= DD;
        const int c = t % CC;
        const int f = t / CC;
        Wp[((f*CC + c)*WW + j)*DD + d] = Wt[idx];
    }
}

// ---------------- projection (grouped conv): f-split grid, f-pairs, b128 LDS reads ----
__global__ __launch_bounds__(256) void conv_kernel(
    const float* __restrict__ x1, const float* __restrict__ x2,
    const float* __restrict__ Wp, bf16_t* __restrict__ q1, bf16_t* __restrict__ q2)
{
    __shared__ float xs[38*512];          // [row][d][c]: addr = row*512 + d*8 + c
    const float* x = blockIdx.z ? x2 : x1;
    bf16_t* q = blockIdx.z ? q2 : q1;
    const float qscale = blockIdx.z ? 1.0f : SCEXP;   // q1 pre-scaled for exp2
    const int n = blockIdx.y;
    const int hb = (blockIdx.x >> 1) * 32;
    const int fh = (blockIdx.x & 1) * 4;  // which 4-fi half this block does
    const int tid = threadIdx.x;

    const float4* xg = (const float4*)(x + (size_t)n*HH*512);
    for (int i = tid; i < 38*128; i += 256) {
        const int row = hb + (i >> 7);
        float4 v = {0.f, 0.f, 0.f, 0.f};
        if (row < HH) v = xg[(size_t)row*128 + (i & 127)];
        const int r = i >> 7;
        const int c = (i & 127) >> 4;
        const int d0 = ((i & 127) & 15) * 4;
        xs[r*512 + (d0+0)*8 + c] = v.x;
        xs[r*512 + (d0+1)*8 + c] = v.y;
        xs[r*512 + (d0+2)*8 + c] = v.z;
        xs[r*512 + (d0+3)*8 + c] = v.w;
    }
    __syncthreads();

    const int d = tid & 63;
    const int fq = tid >> 6;
    for (int fp = 0; fp < 2; ++fp) {      // two f handled together per iteration
        const int f0 = fq*8 + fh + fp*2;
        float w[2][CC][WW];
#pragma unroll
        for (int e = 0; e < 2; ++e)
#pragma unroll
            for (int c = 0; c < CC; ++c)
#pragma unroll
                for (int j = 0; j < WW; ++j)
                    w[e][c][j] = Wp[(((f0+e)*CC + c)*WW + j)*DD + d];
#pragma unroll
        for (int hc = 0; hc < 2; ++hc) {
            float acc[2][16];
#pragma unroll
            for (int e = 0; e < 2; ++e)
#pragma unroll
                for (int i = 0; i < 16; ++i) acc[e][i] = 0.f;
#pragma unroll
            for (int rr = 0; rr < 22; ++rr) {
                const float4 a = *(const float4*)&xs[(hc*16 + rr)*512 + d*8 + 0];
                const float4 b = *(const float4*)&xs[(hc*16 + rr)*512 + d*8 + 4];
                const float xv[8] = {a.x, a.y, a.z, a.w, b.x, b.y, b.z, b.w};
#pragma unroll
                for (int j = 0; j < WW; ++j) {
                    const int i = rr - j;
                    if (i >= 0 && i < 16) {
#pragma unroll
                        for (int c = 0; c < CC; ++c) {
                            acc[0][i] = fmaf(xv[c], w[0][c][j], acc[0][i]);
                            acc[1][i] = fmaf(xv[c], w[1][c][j], acc[1][i]);
                        }
                    }
                }
            }
#pragma unroll
            for (int e = 0; e < 2; ++e)
#pragma unroll
                for (int i = 0; i < 16; ++i) {
                    const int h = hb + hc*16 + i;
                    const float v = (h < HP) ? acc[e][i] * qscale : 0.f;
                    q[((size_t)(n*FF + f0 + e)*HPAD + h)*DD + d] = (bf16_t)v;
                }
    }
    }
}

__device__ __forceinline__ float fast_tanh(float x) {
    const float t = __expf(2.f * x);
    return (t - 1.f) / (t + 1.f);
}

// ---------------- fused flash pass (MFMA), 64 h-rows/wave ----------------
// g-loop unrolled x2 with double-buffered Vt: ONE barrier per 128 g (9 total).
// Sᵀ = Q2·Q1ᵀ : C/D col=lane&31 -> h; row=(reg&3)+8*(reg>>2)+4*(lane>>5) -> g.
// l accumulated by MFMA with all-ones B: every lane holds row-sum at matching reg idx.
template<int MODE>
__global__ __launch_bounds__(256, 2) void flash(
    const bf16_t* __restrict__ q1, const bf16_t* __restrict__ q2,
    const bf16_t* __restrict__ vsrc, bf16_t* __restrict__ p1out,
    float* __restrict__ out)
{
    __shared__ __align__(16) bf16_t Vt[2][2][64*64];   // [buf][tile], 32 KB

    const int head = blockIdx.y;
    const int n = head >> 5, f = head & 31;
    const int tid = threadIdx.x;
    const int w = tid >> 6;
    const int lane = tid & 63;
    const int lid = lane & 31;
    const int half = lane >> 5;
    const int hb = blockIdx.x * 256 + w * 64;

    const size_t qoff = (size_t)head * HPAD * DD;
    const int vswz = (lid & 7) ^ (lid >> 2);

    const int gq = tid >> 4;
    const int dq = tid & 15;
    const int cgb = 4*((gq>>1)&1) + 8*(gq&1) + 16*(gq>>2);

    const bf16_t* vptr = (MODE == 1) ? vsrc : q2;

    // Q1 B-fragments (pre-scaled by SCEXP at conv), persistent
    bf16x8 bq1[2][4];
#pragma unroll
    for (int nt = 0; nt < 2; ++nt)
#pragma unroll
        for (int kt = 0; kt < 4; ++kt)
            bq1[nt][kt] = *(const bf16x8*)&q1[qoff + (size_t)(hb + 32*nt + lid)*DD + 16*kt + 8*half];

    bf16x8 onesb;
#pragma unroll
    for (int j = 0; j < 8; ++j) onesb[j] = (bf16_t)1.0f;

    f32x16 O[2][2] = {};     // [ht][dt]
    f32x16 lO[2]   = {};     // [ht] row-sums of exp

    // ---- prologue: stage pair 0 into buf 0; prefetch pair 1 regs; aq pair 0 ----
    bf16x4 rV[2][4];
#pragma unroll
    for (int t = 0; t < 2; ++t)
#pragma unroll
        for (int i = 0; i < 4; ++i)
            rV[t][i] = *(const bf16x4*)&vptr[qoff + (size_t)(t*64 + 4*gq + i)*DD + 4*dq];
#pragma unroll
    for (int t = 0; t < 2; ++t)
#pragma unroll
        for (int j = 0; j < 4; ++j) {
            bf16x4 c = {rV[t][0][j], rV[t][1][j], rV[t][2][j], rV[t][3][j]};
            *(bf16x4*)&Vt[0][t][vaddr(4*dq + j, cgb)] = c;
        }
#pragma unroll
    for (int t = 0; t < 2; ++t)
#pragma unroll
        for (int i = 0; i < 4; ++i)
            rV[t][i] = *(const bf16x4*)&vptr[qoff + (size_t)(128 + t*64 + 4*gq + i)*DD + 4*dq];

    bf16x8 aq[2][2][4];
#pragma unroll
    for (int t = 0; t < 2; ++t)
#pragma unroll
        for (int mt = 0; mt < 2; ++mt)
#pragma unroll
            for (int kt = 0; kt < 4; ++kt)
                aq[t][mt][kt] = *(const bf16x8*)&q2[qoff + (size_t)(t*64 + 32*mt + lid)*DD + 16*kt + 8*half];

    for (int it = 0; it < 8; ++it) {
        __syncthreads();                  // buf[it&1] complete; buf[it&1 ^1] free
        const int cur = it & 1;
        // stage pair it+1 into the other buffer (regs loaded last iteration)
        if (it < 7) {
#pragma unroll
            for (int t = 0; t < 2; ++t)
#pragma unroll
                for (int j = 0; j < 4; ++j) {
                    bf16x4 c = {rV[t][0][j], rV[t][1][j], rV[t][2][j], rV[t][3][j]};
                    *(bf16x4*)&Vt[cur^1][t][vaddr(4*dq + j, cgb)] = c;
                }
        }
        // prefetch V regs for pair it+2
        if (it < 6) {
            const int base = (it + 2) * 128;
#pragma unroll
            for (int t = 0; t < 2; ++t)
#pragma unroll
                for (int i = 0; i < 4; ++i)
                    rV[t][i] = *(const bf16x4*)&vptr[qoff + (size_t)(base + t*64 + 4*gq + i)*DD + 4*dq];
        }
        // ---- compute the 2 tiles of pair it ----
#pragma unroll
        for (int t = 0; t < 2; ++t) {
            const int g0 = it*128 + t*64;
            const bool tail = (g0 + 64 > HP);
#pragma unroll
            for (int mt = 0; mt < 2; ++mt) {
                f32x16 C[2] = {};
#pragma unroll
                for (int kt = 0; kt < 4; ++kt) {
                    C[0] = __builtin_amdgcn_mfma_f32_32x32x16_bf16(aq[t][mt][kt], bq1[0][kt], C[0], 0,0,0);
                    C[1] = __builtin_amdgcn_mfma_f32_32x32x16_bf16(aq[t][mt][kt], bq1[1][kt], C[1], 0,0,0);
                }
                // reload this slot's A-frags for pair it+1 (long latency window)
                if (it < 7) {
                    const int nb = (it + 1) * 128;
#pragma unroll
                    for (int kt = 0; kt < 4; ++kt)
                        aq[t][mt][kt] = *(const bf16x8*)&q2[qoff + (size_t)(nb + t*64 + 32*mt + lid)*DD + 16*kt + 8*half];
                }
                // exp (q1 pre-scaled: input is C directly) + pack PV A-frags
                bf16x8 af[2][2];
#pragma unroll
                for (int nt = 0; nt < 2; ++nt) {
#pragma unroll
                    for (int s = 0; s < 16; ++s) {
                        float e = EXP2((float)C[nt][s]);
                        if (tail) {
                            const int gg = g0 + 32*mt + (s&3) + 8*(s>>2) + 4*half;
                            if (gg >= HP) e = 0.f;
                        }
                        af[nt][s>>3][s&7] = (bf16_t)e;
                    }
                }
                // l row-sums on the matrix pipe (B = ones)
#pragma unroll
                for (int u = 0; u < 2; ++u) {
                    lO[0] = __builtin_amdgcn_mfma_f32_32x32x16_bf16(af[0][u], onesb, lO[0], 0,0,0);
                    lO[1] = __builtin_amdgcn_mfma_f32_32x32x16_bf16(af[1][u], onesb, lO[1], 0,0,0);
                }
                // PV from swizzled Vt (conflict-free)
#pragma unroll
                for (int u = 0; u < 2; ++u) {
#pragma unroll
                    for (int dt = 0; dt < 2; ++dt) {
                        const int chunk = (4*mt + 2*u + half) ^ vswz;
                        bf16x8 b = *(const bf16x8*)&Vt[cur][t][(32*dt + lid)*64 + chunk*8];
                        O[0][dt] = __builtin_amdgcn_mfma_f32_32x32x16_bf16(af[0][u], b, O[0][dt], 0,0,0);
                        O[1][dt] = __builtin_amdgcn_mfma_f32_32x32x16_bf16(af[1][u], b, O[1][dt], 0,0,0);
                    }
                }
            }
        }
    }

    // ---- epilogue: elementwise normalize (lO lanes already hold row sums) ----
#pragma unroll
    for (int ht = 0; ht < 2; ++ht) {
#pragma unroll
        for (int s = 0; s < 16; ++s) {
            const int R = (s&3) + 8*(s>>2) + 4*half;
            const int hg = hb + 32*ht + R;
            const float linv = 1.f / lO[ht][s];
#pragma unroll
            for (int dt = 0; dt < 2; ++dt) {
                const int d = 32*dt + lid;
                const float val = O[ht][dt][s] * linv;
                if (hg < HP)
                    out[(((size_t)n*HP + hg)*FF + f)*DD + d] = fast_tanh(val);
                if (MODE == 0)
                    p1out[qoff + (size_t)hg*DD + d] = (bf16_t)(hg < HP ? val : 0.f);
            }
        }
    }
}

extern "C" void kernel_launch(void* const* d_in, const int* in_sizes, int n_in,
                              void* d_out, int out_size, void* d_ws, size_t ws_size,
                              hipStream_t stream)
{
    const float* prot1 = (const float*)d_in[0];
    const float* prot2 = (const float*)d_in[1];
    const float* Wt    = (const float*)d_in[2];
    float* out = (float*)d_out;

    bf16_t* q1b = (bf16_t*)d_ws;
    bf16_t* q2b = q1b + QWS;
    bf16_t* p1b = q2b + QWS;
    float* Wp   = (float*)(p1b + QWS);

    wprep_kernel<<<dim3(448), 256, 0, stream>>>(Wt, Wp);
    conv_kernel<<<dim3(64, 4, 2), 256, 0, stream>>>(prot1, prot2, Wp, q1b, q2b);
    flash<0><<<dim3(4, NF), 256, 0, stream>>>(q1b, q2b, q2b, p1b, out);
    flash<1><<<dim3(4, NF), 256, 0, stream>>>(q1b, q2b, p1b, p1b, out + QOUT);
}

// Round 7
// 248.497 us; speedup vs baseline: 1.2721x; 1.2721x over previous
//
#include <hip/hip_runtime.h>
#include <math.h>

typedef __bf16 bf16_t;
typedef bf16_t bf16x4 __attribute__((ext_vector_type(4)));
typedef bf16_t bf16x8 __attribute__((ext_vector_type(8)));
typedef float  f32x16 __attribute__((ext_vector_type(16)));

#define HH 1024
#define CC 8
#define DD 64
#define FF 32
#define WW 7
#define HP 1018
#define HPAD 1024
#define NF 128
#define QOUT (NF*HP*DD)
#define QWS ((size_t)NF*HPAD*DD)
#define SCEXP (1.442695041f/1018.f)     // log2(e)/1018, pre-applied to q1

#if __has_builtin(__builtin_amdgcn_exp2f)
#define EXP2(x) __builtin_amdgcn_exp2f(x)
#else
#define EXP2(x) __expf((x) * 0.6931471805599453f)
#endif

// Vt: row stride 64 bf16, XOR-swizzled 8-element chunks (validated R4/R5):
__device__ __forceinline__ int vaddr(int row, int col) {
    return row*64 + ((((col>>3) ^ (row&7) ^ ((row>>2)&7)))<<3) + (col&7);
}

// ---------------- W transpose: Wt[f][c][d][j] -> Wp[f][c][j][d] ----------------
__global__ __launch_bounds__(256) void wprep_kernel(
    const float* __restrict__ Wt, float* __restrict__ Wp)
{
    const int idx = blockIdx.x * 256 + threadIdx.x;
    if (idx < FF*CC*DD*WW) {
        const int j = idx % WW;
        int t = idx / WW;
        const int d = t % DD; t /= DD;
        const int c = t % CC;
        const int f = t / CC;
        Wp[((f*CC + c)*WW + j)*DD + d] = Wt[idx];
    }
}

// ---------------- x transpose: x[n][row][c][d] fp32 -> xt[z][n][row][d][c] bf16 ----
__global__ __launch_bounds__(256) void xprep_kernel(
    const float* __restrict__ x1, const float* __restrict__ x2,
    bf16_t* __restrict__ xt)
{
    __shared__ float ls[8][CC][DD+1];     // pad -> 2-way max on both phases
    const float* x = blockIdx.z ? x2 : x1;
    bf16_t* o = xt + (size_t)blockIdx.z * (4*HH*512);
    const int n = blockIdx.y;
    const int r0 = blockIdx.x * 8;
    const int tid = threadIdx.x;

#pragma unroll
    for (int it = 0; it < 4; ++it) {
        const int i = it*256 + tid;       // 0..1023 : 8 rows x 128 float4
        const int r = i >> 7;
        const int idx = i & 127;
        const int c = idx >> 4;
        const int d0 = (idx & 15) * 4;
        float4 v = *(const float4*)&x[((size_t)(n*HH + r0 + r)*CC + c)*DD + d0];
        ls[r][c][d0+0] = v.x; ls[r][c][d0+1] = v.y;
        ls[r][c][d0+2] = v.z; ls[r][c][d0+3] = v.w;
    }
    __syncthreads();
    const int d = tid & 63;
    for (int r = (tid >> 6); r < 8; r += 4) {
        bf16_t tmp[8];
#pragma unroll
        for (int c = 0; c < CC; ++c) tmp[c] = (bf16_t)ls[r][c][d];
        *(bf16x8*)&o[((size_t)(n*HH + r0 + r)*DD + d)*CC] = *(bf16x8*)tmp;
    }
}

// ---------------- projection (grouped conv) from transposed bf16 x ----------------
// block = 64 d-lanes x 4 f-groups; 16 h rows per block; xs staged by linear b128 copy.
__global__ __launch_bounds__(256) void conv_kernel(
    const bf16_t* __restrict__ xt, const float* __restrict__ Wp,
    bf16_t* __restrict__ q1, bf16_t* __restrict__ q2)
{
    __shared__ __align__(16) bf16_t xs[22*64*8];   // [rr][d][c], 22528 B
    const int z = blockIdx.z;
    const bf16_t* xb = xt + (size_t)z * (4*HH*512);
    bf16_t* q = z ? q2 : q1;
    const float qscale = z ? 1.0f : SCEXP;         // q1 pre-scaled for exp2
    const int n = blockIdx.y;
    const int hb = blockIdx.x * 16;
    const int tid = threadIdx.x;

    // stage rows hb..hb+21 (16 outputs need 22 input rows), linear = conflict-free
    for (int i = tid; i < 22*64; i += 256) {       // (row,d) chunks of 8 bf16 = 16 B
        const int row = hb + (i >> 6);
        const int dd = i & 63;
        bf16x8 v = {};
        if (row < HH) v = *(const bf16x8*)&xb[((size_t)(n*HH + row)*DD + dd)*CC];
        *(bf16x8*)&xs[(size_t)i*8] = v;
    }
    __syncthreads();

    const int d = tid & 63;
    const int fq = tid >> 6;
    for (int fi = 0; fi < 8; ++fi) {
        const int f = fq*8 + fi;
        float w[CC][WW];
#pragma unroll
        for (int c = 0; c < CC; ++c)
#pragma unroll
            for (int j = 0; j < WW; ++j)
                w[c][j] = Wp[((f*CC + c)*WW + j)*DD + d];
        float acc[16];
#pragma unroll
        for (int i = 0; i < 16; ++i) acc[i] = 0.f;
#pragma unroll
        for (int rr = 0; rr < 22; ++rr) {
            bf16x8 xv8 = *(const bf16x8*)&xs[(rr*64 + d)*8];
            float xv[8];
#pragma unroll
            for (int c = 0; c < CC; ++c) xv[c] = (float)xv8[c];
#pragma unroll
            for (int j = 0; j < WW; ++j) {
                const int i = rr - j;
                if (i >= 0 && i < 16) {
#pragma unroll
                    for (int c = 0; c < CC; ++c)
                        acc[i] = fmaf(xv[c], w[c][j], acc[i]);
                }
            }
        }
#pragma unroll
        for (int i = 0; i < 16; ++i) {
            const int h = hb + i;
            const float v = (h < HP) ? acc[i] * qscale : 0.f;
            q[((size_t)(n*FF + f)*HPAD + h)*DD + d] = (bf16_t)v;
        }
    }
}

__device__ __forceinline__ float fast_tanh(float x) {
    const float t = __expf(2.f * x);
    return (t - 1.f) / (t + 1.f);
}

// ---------------- fused flash pass (MFMA), 64 h-rows/wave (R5 structure) ----------
// Sᵀ = Q2·Q1ᵀ : C/D col=lane&31 -> h; row=(reg&3)+8*(reg>>2)+4*(lane>>5) -> g.
// A-frags from global (L1/L2-hot, prefetched); Vt in swizzled LDS.
// l row-sums accumulated on the MATRIX pipe via B=ones MFMA: lO[ht] reg s holds
// the softmax denominator for the same row h as O[ht][dt] reg s -> no shuffles.
template<int MODE>
__global__ __launch_bounds__(256, 2) void flash(
    const bf16_t* __restrict__ q1, const bf16_t* __restrict__ q2,
    const bf16_t* __restrict__ vsrc, bf16_t* __restrict__ p1out,
    float* __restrict__ out)
{
    __shared__ __align__(16) bf16_t Vt[64*64];     // V^T tile [d][p(g)], swizzled

    const int head = blockIdx.y;
    const int n = head >> 5, f = head & 31;
    const int tid = threadIdx.x;
    const int w = tid >> 6;
    const int lane = tid & 63;
    const int lid = lane & 31;
    const int half = lane >> 5;
    const int hb = blockIdx.x * 256 + w * 64;

    const size_t qoff = (size_t)head * HPAD * DD;
    const int vswz = (lid & 7) ^ (lid >> 2);

    const int gq = tid >> 4;
    const int dq = tid & 15;
    const int cgb = 4*((gq>>1)&1) + 8*(gq&1) + 16*(gq>>2);

    const bf16_t* vptr = (MODE == 1) ? vsrc : q2;

    // Q1 B-fragments (pre-scaled by SCEXP in conv), persistent
    bf16x8 bq1[2][4];
#pragma unroll
    for (int nt = 0; nt < 2; ++nt)
#pragma unroll
        for (int kt = 0; kt < 4; ++kt)
            bq1[nt][kt] = *(const bf16x8*)&q1[qoff + (size_t)(hb + 32*nt + lid)*DD + 16*kt + 8*half];

    bf16x8 onesb;
#pragma unroll
    for (int j = 0; j < 8; ++j) onesb[j] = (bf16_t)1.0f;

    // A-fragments for tile 0 (from global)
    bf16x8 aq[2][4];
#pragma unroll
    for (int mt = 0; mt < 2; ++mt)
#pragma unroll
        for (int kt = 0; kt < 4; ++kt)
            aq[mt][kt] = *(const bf16x8*)&q2[qoff + (size_t)(32*mt + lid)*DD + 16*kt + 8*half];

    // V staging regs for tile 0
    bf16x4 rV[4];
#pragma unroll
    for (int i = 0; i < 4; ++i)
        rV[i] = *(const bf16x4*)&vptr[qoff + (size_t)(4*gq + i)*DD + 4*dq];

    f32x16 O[2][2] = {};
    f32x16 lO[2] = {};

    for (int g0 = 0; g0 < HPAD; g0 += 64) {
        __syncthreads();                           // prev Vt fully consumed
#pragma unroll
        for (int j = 0; j < 4; ++j) {
            bf16x4 c = { rV[0][j], rV[1][j], rV[2][j], rV[3][j] };
            *(bf16x4*)&Vt[vaddr(4*dq + j, cgb)] = c;
        }
        __syncthreads();

        // prefetch next V tile
        if (g0 + 64 < HPAD) {
#pragma unroll
            for (int i = 0; i < 4; ++i)
                rV[i] = *(const bf16x4*)&vptr[qoff + (size_t)(g0 + 64 + 4*gq + i)*DD + 4*dq];
        }

        const bool tail = (g0 + 64 > HP);

#pragma unroll
        for (int mt = 0; mt < 2; ++mt) {
            // ---- S-phase ----
            f32x16 C[2] = {};
#pragma unroll
            for (int kt = 0; kt < 4; ++kt) {
                C[0] = __builtin_amdgcn_mfma_f32_32x32x16_bf16(aq[mt][kt], bq1[0][kt], C[0], 0,0,0);
                C[1] = __builtin_amdgcn_mfma_f32_32x32x16_bf16(aq[mt][kt], bq1[1][kt], C[1], 0,0,0);
            }
            // reload this mt's A-frags for the NEXT tile (long latency window)
            if (g0 + 64 < HPAD) {
#pragma unroll
                for (int kt = 0; kt < 4; ++kt)
                    aq[mt][kt] = *(const bf16x8*)&q2[qoff + (size_t)(g0 + 64 + 32*mt + lid)*DD + 16*kt + 8*half];
            }
            // ---- exp (q1 pre-scaled) + pack PV A-frags ----
            bf16x8 af[2][2];
#pragma unroll
            for (int nt = 0; nt < 2; ++nt) {
#pragma unroll
                for (int s = 0; s < 16; ++s) {
                    float e = EXP2((float)C[nt][s]);
                    if (tail) {
                        const int gg = g0 + 32*mt + (s&3) + 8*(s>>2) + 4*half;
                        if (gg >= HP) e = 0.f;
                    }
                    af[nt][s>>3][s&7] = (bf16_t)e;
                }
            }
            // ---- l row-sums on the matrix pipe (B = ones) ----
#pragma unroll
            for (int u = 0; u < 2; ++u) {
                lO[0] = __builtin_amdgcn_mfma_f32_32x32x16_bf16(af[0][u], onesb, lO[0], 0,0,0);
                lO[1] = __builtin_amdgcn_mfma_f32_32x32x16_bf16(af[1][u], onesb, lO[1], 0,0,0);
            }
            // ---- PV: swizzled Vt b128 reads (conflict-free) ----
#pragma unroll
            for (int u = 0; u < 2; ++u) {
#pragma unroll
                for (int dt = 0; dt < 2; ++dt) {
                    const int chunk = (4*mt + 2*u + half) ^ vswz;
                    bf16x8 b = *(const bf16x8*)&Vt[(32*dt + lid)*64 + chunk*8];
                    O[0][dt] = __builtin_amdgcn_mfma_f32_32x32x16_bf16(af[0][u], b, O[0][dt], 0,0,0);
                    O[1][dt] = __builtin_amdgcn_mfma_f32_32x32x16_bf16(af[1][u], b, O[1][dt], 0,0,0);
                }
            }
        }
    }

    // ---- epilogue: lO reg s matches O reg s (same row h) -> elementwise ----
#pragma unroll
    for (int ht = 0; ht < 2; ++ht) {
#pragma unroll
        for (int s = 0; s < 16; ++s) {
            const int R = (s&3) + 8*(s>>2) + 4*half;
            const int hg = hb + 32*ht + R;
            const float linv = 1.f / lO[ht][s];
#pragma unroll
            for (int dt = 0; dt < 2; ++dt) {
                const int d = 32*dt + lid;
                const float val = O[ht][dt][s] * linv;
                if (hg < HP)
                    out[(((size_t)n*HP + hg)*FF + f)*DD + d] = fast_tanh(val);
                if (MODE == 0)   // zero-pad p1 rows >= HP for pass B staging
                    p1out[qoff + (size_t)hg*DD + d] = (bf16_t)(hg < HP ? val : 0.f);
            }
        }
    }
}

extern "C" void kernel_launch(void* const* d_in, const int* in_sizes, int n_in,
                              void* d_out, int out_size, void* d_ws, size_t ws_size,
                              hipStream_t stream)
{
    const float* prot1 = (const float*)d_in[0];
    const float* prot2 = (const float*)d_in[1];
    const float* Wt    = (const float*)d_in[2];
    float* out = (float*)d_out;

    bf16_t* q1b = (bf16_t*)d_ws;
    bf16_t* q2b = q1b + QWS;
    bf16_t* p1b = q2b + QWS;
    float*  Wp  = (float*)(p1b + QWS);             // FF*CC*DD*WW floats
    bf16_t* xtb = (bf16_t*)(Wp + FF*CC*DD*WW);     // 2 * 4*HH*512 bf16 = 8 MB

    wprep_kernel<<<dim3(448), 256, 0, stream>>>(Wt, Wp);
    xprep_kernel<<<dim3(HH/8, 4, 2), 256, 0, stream>>>(prot1, prot2, xtb);
    conv_kernel<<<dim3(64, 4, 2), 256, 0, stream>>>(xtb, Wp, q1b, q2b);
    flash<0><<<dim3(4, NF), 256, 0, stream>>>(q1b, q2b, q2b, p1b, out);
    flash<1><<<dim3(4, NF), 256, 0, stream>>>(q1b, q2b, p1b, p1b, out + QOUT);
}